// Round 10
// baseline (9023.433 us; speedup 1.0000x reference)
//
#include <hip/hip_runtime.h>
#include <math.h>

#define N_NODES 100000
#define N_EDGES 3200000
#define BS 256
#define CAP_SHIFT 7            // 128 bucket slots per node; max deg ~59
#define CAP (1 << CAP_SHIFT)
#define SLOTF 2000000          // ring slot = 8MB (holds any layer state)
#define OFF1 800000            // state group-1 offset (floats)
#define OFF2 1600000           // state group-2 offset (floats, L3 only)

// ==================== deterministic all-f32 data path ====================
// Rounding-matched to numpy (absmax 0 at r14/r16/r17/r19):
//  - bucket sums in ascending edge-id order; SpMV products rounded then added
//  - matmuls ascending-ci fmaf chains from 0; acc adds ascending k
//  - dis = 1/sqrtf.  ONLY ADDRESSES may change between rounds.
//
// Ledger: r14 8148 | r16 seq-groups -37% | r17 phased-fill null | r18 nt+scalar
// -2.3x (confounded) | r19 7684 (LDS sort fusion) | r20 infra-fail (this kernel,
// never ran). r21 = r20 resubmit: CLEAN XCD test: L2/L3 props channel-split
// across BLOCKS (blockIdx%2 / %8 -> XCD sets, each group array <=3.2MB ->
// per-XCD L2 resident), plain loads, matmul deferred to batched mm kernels
// (every 4 steps, tx ring of 6, in-order stream = race-free, acc adds still
// ascending k). L1 (0.8MB state, already resident) stays fused.

__global__ void scan_partial_kernel(const int* __restrict__ cnt, int* __restrict__ bsums) {
    __shared__ int lds[256];
    int tid = threadIdx.x;
    int base = blockIdx.x * 1024 + tid * 4;
    int s = 0;
#pragma unroll
    for (int i = 0; i < 4; ++i) s += (base + i < N_NODES) ? cnt[base + i] : 0;
    lds[tid] = s;
    __syncthreads();
    for (int off = 128; off > 0; off >>= 1) {
        if (tid < off) lds[tid] += lds[tid + off];
        __syncthreads();
    }
    if (tid == 0) bsums[blockIdx.x] = lds[0];
}

__global__ void scan_bsums_kernel(int* __restrict__ bsums, int nb, int* __restrict__ total_out) {
    if (threadIdx.x == 0 && blockIdx.x == 0) {
        int acc = 0;
        for (int b = 0; b < nb; ++b) {
            int v = bsums[b];
            bsums[b] = acc;
            acc += v;
        }
        *total_out = acc;
    }
}

__global__ void scan_final_kernel(const int* __restrict__ cnt, const int* __restrict__ bsums,
                                  int* __restrict__ rp) {
    __shared__ int lds[256];
    int tid = threadIdx.x;
    int base = blockIdx.x * 1024 + tid * 4;
    int v[4];
    int ts = 0;
#pragma unroll
    for (int i = 0; i < 4; ++i) {
        v[i] = (base + i < N_NODES) ? cnt[base + i] : 0;
        ts += v[i];
    }
    lds[tid] = ts;
    __syncthreads();
    for (int off = 1; off < 256; off <<= 1) {
        int t = (tid >= off) ? lds[tid - off] : 0;
        __syncthreads();
        lds[tid] += t;
        __syncthreads();
    }
    int run = lds[tid] - ts + bsums[blockIdx.x];
#pragma unroll
    for (int i = 0; i < 4; ++i) {
        if (base + i < N_NODES) rp[base + i] = run;
        run += v[i];
    }
}

__global__ void fill_direct_kernel(const int* __restrict__ src, const int* __restrict__ dst,
                                   int* __restrict__ cnt_s, int* __restrict__ cnt_d,
                                   int* __restrict__ bkt_s, int* __restrict__ bkt_d) {
    int e = blockIdx.x * blockDim.x + threadIdx.x;
    if (e >= N_EDGES) return;
    int s = src[e];
    int d = dst[e];
    int slot_s = atomicAdd(&cnt_s[s], 1);
    bkt_s[((size_t)s << CAP_SHIFT) + slot_s] = e;
    int slot_d = atomicAdd(&cnt_d[d], 1);
    bkt_d[((size_t)d << CAP_SHIFT) + slot_d] = e;
}

// src-side: LDS-staged rank-sort by edge id, then ordered deg sum -> dis.
__global__ __launch_bounds__(64) void sort_deg_dis_kernel(
    const int* __restrict__ cnt, const int* __restrict__ bkt,
    const float* __restrict__ w, float* __restrict__ dis) {
#pragma clang fp contract(off)
    {
        __shared__ int lr[64][65];
        __shared__ int ls[64][65];
        int n = blockIdx.x * 64 + threadIdx.x;
        if (n >= N_NODES) return;
        int c = cnt[n];
        const int* row = bkt + ((size_t)n << CAP_SHIFT);
        float d = 0.f;
        if (c <= 64) {
            int* a = lr[threadIdx.x];
            int* b = ls[threadIdx.x];
            for (int i = 0; i < c; ++i) a[i] = row[i];
            for (int i = 0; i < c; ++i) {
                int v = a[i];
                int rk = 0;
                for (int j = 0; j < c; ++j) rk += (a[j] < v);
                b[rk] = v;
            }
            for (int r = 0; r < c; ++r) d = d + w[b[r]];
        } else {
            for (int r = 0; r < c; ++r) {
                for (int i = 0; i < c; ++i) {
                    int v = row[i];
                    int rk = 0;
                    for (int j = 0; j < c; ++j) rk += (row[j] < v);
                    if (rk == r) { d = d + w[v]; break; }
                }
            }
        }
        dis[n] = (d > 0.f) ? (1.0f / sqrtf(d)) : 0.f;
    }
}

// dst-side: LDS-staged rank-sort, emit packed[beg+r] = {src, ((-dis[s])*w)*dis[n]}.
__global__ __launch_bounds__(64) void sort_pack_kernel(
    const int* __restrict__ cnt, const int* __restrict__ rp,
    const int* __restrict__ bkt, const int* __restrict__ src,
    const float* __restrict__ w, const float* __restrict__ dis,
    int2* __restrict__ packed) {
#pragma clang fp contract(off)
    {
        __shared__ int lr[64][65];
        __shared__ int ls[64][65];
        int n = blockIdx.x * 64 + threadIdx.x;
        if (n >= N_NODES) return;
        int c = cnt[n];
        const int* row = bkt + ((size_t)n << CAP_SHIFT);
        int beg = rp[n];
        float din = dis[n];
        if (c <= 64) {
            int* a = lr[threadIdx.x];
            int* b = ls[threadIdx.x];
            for (int i = 0; i < c; ++i) a[i] = row[i];
            for (int i = 0; i < c; ++i) {
                int v = a[i];
                int rk = 0;
                for (int j = 0; j < c; ++j) rk += (a[j] < v);
                b[rk] = v;
            }
            for (int r = 0; r < c; ++r) {
                int e = b[r];
                int s = src[e];
                float cw = ((-dis[s]) * w[e]) * din;
                packed[beg + r] = make_int2(s, __float_as_int(cw));
            }
        } else {
            for (int r = 0; r < c; ++r) {
                for (int i = 0; i < c; ++i) {
                    int v = row[i];
                    int rk = 0;
                    for (int j = 0; j < c; ++j) rk += (row[j] < v);
                    if (rk == r) {
                        int s = src[v];
                        float cw = ((-dis[s]) * w[v]) * din;
                        packed[beg + r] = make_int2(s, __float_as_int(cw));
                        break;
                    }
                }
            }
        }
    }
}

// ==================== split-state addressing ====================
// L1/L2 state (14ch): {8ch S8 @0 | 6ch+2pad S8 @OFF1}  (pads zeroed once)
// L3 state (20ch):    {8ch S8 @0 | 8ch S8 @OFF1 | 4ch S4 @OFF2}
__device__ __forceinline__ size_t addrA(int n, int c) {
    return (c < 8) ? ((size_t)n * 8 + c) : (OFF1 + (size_t)n * 8 + (c - 8));
}
__device__ __forceinline__ size_t addrB(int n, int c) {
    return (c < 8) ? ((size_t)n * 8 + c)
         : (c < 16) ? (OFF1 + (size_t)n * 8 + (c - 8))
                    : (OFF2 + (size_t)n * 4 + (c - 16));
}

// ==================== gather chains (plain loads, ascending edge id) ====================
template <int S>
__device__ __forceinline__ void gather4_u8(const float* __restrict__ a, int c0,
                                           const int2* __restrict__ pk, int beg, int end,
                                           float s[4]) {
#pragma clang fp contract(off)
    {
        int j = beg;
        for (; j + 7 < end; j += 8) {
            int2 p0 = pk[j];
            int2 p1 = pk[j + 1];
            int2 p2 = pk[j + 2];
            int2 p3 = pk[j + 3];
            int2 p4 = pk[j + 4];
            int2 p5 = pk[j + 5];
            int2 p6 = pk[j + 6];
            int2 p7 = pk[j + 7];
            const float4 q0 = *reinterpret_cast<const float4*>(a + (size_t)p0.x * S + c0);
            const float4 q1 = *reinterpret_cast<const float4*>(a + (size_t)p1.x * S + c0);
            const float4 q2 = *reinterpret_cast<const float4*>(a + (size_t)p2.x * S + c0);
            const float4 q3 = *reinterpret_cast<const float4*>(a + (size_t)p3.x * S + c0);
            const float4 q4 = *reinterpret_cast<const float4*>(a + (size_t)p4.x * S + c0);
            const float4 q5 = *reinterpret_cast<const float4*>(a + (size_t)p5.x * S + c0);
            const float4 q6 = *reinterpret_cast<const float4*>(a + (size_t)p6.x * S + c0);
            const float4 q7 = *reinterpret_cast<const float4*>(a + (size_t)p7.x * S + c0);
            float w0 = __int_as_float(p0.y), w1 = __int_as_float(p1.y);
            float w2 = __int_as_float(p2.y), w3 = __int_as_float(p3.y);
            float w4 = __int_as_float(p4.y), w5 = __int_as_float(p5.y);
            float w6 = __int_as_float(p6.y), w7 = __int_as_float(p7.y);
            s[0] = s[0] + (w0 * q0.x); s[1] = s[1] + (w0 * q0.y);
            s[2] = s[2] + (w0 * q0.z); s[3] = s[3] + (w0 * q0.w);
            s[0] = s[0] + (w1 * q1.x); s[1] = s[1] + (w1 * q1.y);
            s[2] = s[2] + (w1 * q1.z); s[3] = s[3] + (w1 * q1.w);
            s[0] = s[0] + (w2 * q2.x); s[1] = s[1] + (w2 * q2.y);
            s[2] = s[2] + (w2 * q2.z); s[3] = s[3] + (w2 * q2.w);
            s[0] = s[0] + (w3 * q3.x); s[1] = s[1] + (w3 * q3.y);
            s[2] = s[2] + (w3 * q3.z); s[3] = s[3] + (w3 * q3.w);
            s[0] = s[0] + (w4 * q4.x); s[1] = s[1] + (w4 * q4.y);
            s[2] = s[2] + (w4 * q4.z); s[3] = s[3] + (w4 * q4.w);
            s[0] = s[0] + (w5 * q5.x); s[1] = s[1] + (w5 * q5.y);
            s[2] = s[2] + (w5 * q5.z); s[3] = s[3] + (w5 * q5.w);
            s[0] = s[0] + (w6 * q6.x); s[1] = s[1] + (w6 * q6.y);
            s[2] = s[2] + (w6 * q6.z); s[3] = s[3] + (w6 * q6.w);
            s[0] = s[0] + (w7 * q7.x); s[1] = s[1] + (w7 * q7.y);
            s[2] = s[2] + (w7 * q7.z); s[3] = s[3] + (w7 * q7.w);
        }
        for (; j + 3 < end; j += 4) {
            int2 p0 = pk[j];
            int2 p1 = pk[j + 1];
            int2 p2 = pk[j + 2];
            int2 p3 = pk[j + 3];
            const float4 q0 = *reinterpret_cast<const float4*>(a + (size_t)p0.x * S + c0);
            const float4 q1 = *reinterpret_cast<const float4*>(a + (size_t)p1.x * S + c0);
            const float4 q2 = *reinterpret_cast<const float4*>(a + (size_t)p2.x * S + c0);
            const float4 q3 = *reinterpret_cast<const float4*>(a + (size_t)p3.x * S + c0);
            float w0 = __int_as_float(p0.y), w1 = __int_as_float(p1.y);
            float w2 = __int_as_float(p2.y), w3 = __int_as_float(p3.y);
            s[0] = s[0] + (w0 * q0.x); s[1] = s[1] + (w0 * q0.y);
            s[2] = s[2] + (w0 * q0.z); s[3] = s[3] + (w0 * q0.w);
            s[0] = s[0] + (w1 * q1.x); s[1] = s[1] + (w1 * q1.y);
            s[2] = s[2] + (w1 * q1.z); s[3] = s[3] + (w1 * q1.w);
            s[0] = s[0] + (w2 * q2.x); s[1] = s[1] + (w2 * q2.y);
            s[2] = s[2] + (w2 * q2.z); s[3] = s[3] + (w2 * q2.w);
            s[0] = s[0] + (w3 * q3.x); s[1] = s[1] + (w3 * q3.y);
            s[2] = s[2] + (w3 * q3.z); s[3] = s[3] + (w3 * q3.w);
        }
        for (; j < end; ++j) {
            int2 p = pk[j];
            float w = __int_as_float(p.y);
            const float4 q = *reinterpret_cast<const float4*>(a + (size_t)p.x * S + c0);
            s[0] = s[0] + (w * q.x); s[1] = s[1] + (w * q.y);
            s[2] = s[2] + (w * q.z); s[3] = s[3] + (w * q.w);
        }
    }
}

__device__ __forceinline__ void gather2_u8s2(const float* __restrict__ a,
                                             const int2* __restrict__ pk, int beg, int end,
                                             float s[2]) {
#pragma clang fp contract(off)
    {
        int j = beg;
        for (; j + 7 < end; j += 8) {
            int2 p0 = pk[j];
            int2 p1 = pk[j + 1];
            int2 p2 = pk[j + 2];
            int2 p3 = pk[j + 3];
            int2 p4 = pk[j + 4];
            int2 p5 = pk[j + 5];
            int2 p6 = pk[j + 6];
            int2 p7 = pk[j + 7];
            const float2 q0 = *reinterpret_cast<const float2*>(a + (size_t)p0.x * 2);
            const float2 q1 = *reinterpret_cast<const float2*>(a + (size_t)p1.x * 2);
            const float2 q2 = *reinterpret_cast<const float2*>(a + (size_t)p2.x * 2);
            const float2 q3 = *reinterpret_cast<const float2*>(a + (size_t)p3.x * 2);
            const float2 q4 = *reinterpret_cast<const float2*>(a + (size_t)p4.x * 2);
            const float2 q5 = *reinterpret_cast<const float2*>(a + (size_t)p5.x * 2);
            const float2 q6 = *reinterpret_cast<const float2*>(a + (size_t)p6.x * 2);
            const float2 q7 = *reinterpret_cast<const float2*>(a + (size_t)p7.x * 2);
            float w0 = __int_as_float(p0.y), w1 = __int_as_float(p1.y);
            float w2 = __int_as_float(p2.y), w3 = __int_as_float(p3.y);
            float w4 = __int_as_float(p4.y), w5 = __int_as_float(p5.y);
            float w6 = __int_as_float(p6.y), w7 = __int_as_float(p7.y);
            s[0] = s[0] + (w0 * q0.x); s[1] = s[1] + (w0 * q0.y);
            s[0] = s[0] + (w1 * q1.x); s[1] = s[1] + (w1 * q1.y);
            s[0] = s[0] + (w2 * q2.x); s[1] = s[1] + (w2 * q2.y);
            s[0] = s[0] + (w3 * q3.x); s[1] = s[1] + (w3 * q3.y);
            s[0] = s[0] + (w4 * q4.x); s[1] = s[1] + (w4 * q4.y);
            s[0] = s[0] + (w5 * q5.x); s[1] = s[1] + (w5 * q5.y);
            s[0] = s[0] + (w6 * q6.x); s[1] = s[1] + (w6 * q6.y);
            s[0] = s[0] + (w7 * q7.x); s[1] = s[1] + (w7 * q7.y);
        }
        for (; j + 3 < end; j += 4) {
            int2 p0 = pk[j];
            int2 p1 = pk[j + 1];
            int2 p2 = pk[j + 2];
            int2 p3 = pk[j + 3];
            const float2 q0 = *reinterpret_cast<const float2*>(a + (size_t)p0.x * 2);
            const float2 q1 = *reinterpret_cast<const float2*>(a + (size_t)p1.x * 2);
            const float2 q2 = *reinterpret_cast<const float2*>(a + (size_t)p2.x * 2);
            const float2 q3 = *reinterpret_cast<const float2*>(a + (size_t)p3.x * 2);
            float w0 = __int_as_float(p0.y), w1 = __int_as_float(p1.y);
            float w2 = __int_as_float(p2.y), w3 = __int_as_float(p3.y);
            s[0] = s[0] + (w0 * q0.x); s[1] = s[1] + (w0 * q0.y);
            s[0] = s[0] + (w1 * q1.x); s[1] = s[1] + (w1 * q1.y);
            s[0] = s[0] + (w2 * q2.x); s[1] = s[1] + (w2 * q2.y);
            s[0] = s[0] + (w3 * q3.x); s[1] = s[1] + (w3 * q3.y);
        }
        for (; j < end; ++j) {
            int2 p = pk[j];
            float w = __int_as_float(p.y);
            const float2 q = *reinterpret_cast<const float2*>(a + (size_t)p.x * 2);
            s[0] = s[0] + (w * q.x); s[1] = s[1] + (w * q.y);
        }
    }
}

// ==================== L1: fused prop+matmul (state 0.8MB, already L2-resident) ====================
__global__ __launch_bounds__(256) void prop_l1_kernel(
    const int* __restrict__ rp, const int2* __restrict__ pk, const float* __restrict__ hin,
    const float* __restrict__ prev, const float* __restrict__ Wk, int rec,
    float* __restrict__ tx_out, float* __restrict__ acc) {
#pragma clang fp contract(off)
    {
        int n = blockIdx.x * 256 + threadIdx.x;
        if (n >= N_NODES) return;
        float s[2] = {0.f, 0.f};
        int beg = rp[n], end = rp[n + 1];
        gather2_u8s2(hin, pk, beg, end, s);
        float t0v, t1v;
        if (rec) {
            const float2 pv = *reinterpret_cast<const float2*>(prev + (size_t)n * 2);
            t0v = 2.f * s[0] - pv.x;
            t1v = 2.f * s[1] - pv.y;
        } else {
            t0v = s[0];
            t1v = s[1];
        }
        *reinterpret_cast<float2*>(tx_out + (size_t)n * 2) = make_float2(t0v, t1v);
        for (int co = 0; co < 14; ++co) {
            float m = 0.f;
            m = fmaf(t0v, Wk[co], m);
            m = fmaf(t1v, Wk[14 + co], m);
            size_t a = addrA(n, co);
            acc[a] = acc[a] + m;
        }
    }
}

// ==================== L2/L3: XCD-channel-split prop (tx only, no matmul) ====================
template <int LAYER>
__global__ __launch_bounds__(256) void prop_split_kernel(
    const int* __restrict__ rp, const int2* __restrict__ pk,
    const float* __restrict__ pm1, const float* __restrict__ pm2,
    float* __restrict__ tx, int rec) {
#pragma clang fp contract(off)
    {
        int b = blockIdx.x;
        int n;
        int c0;
        size_t goff;
        int S;
        bool s4 = false;
        if constexpr (LAYER == 2) {
            int g = b & 1;               // group -> even/odd XCDs
            int tile = b >> 1;           // < 782
            n = tile * 128 + (threadIdx.x >> 1);
            c0 = (threadIdx.x & 1) * 4;
            goff = g ? (size_t)OFF1 : 0;
            S = 8;
        } else {
            int slot = b & 7;            // XCD slots {0-2}->g0 {3-5}->g1 {6-7}->g2
            int p = b >> 3;
            if (slot < 3) {
                int tile = p * 3 + slot;
                if (tile >= 782) return;
                n = tile * 128 + (threadIdx.x >> 1);
                c0 = (threadIdx.x & 1) * 4;
                goff = 0;
                S = 8;
            } else if (slot < 6) {
                int tile = p * 3 + (slot - 3);
                if (tile >= 782) return;
                n = tile * 128 + (threadIdx.x >> 1);
                c0 = (threadIdx.x & 1) * 4;
                goff = OFF1;
                S = 8;
            } else {
                int tile = p * 2 + (slot - 6);
                if (tile >= 391) return;
                n = tile * 256 + threadIdx.x;
                c0 = 0;
                goff = OFF2;
                S = 4;
                s4 = true;
            }
        }
        if (n >= N_NODES) return;
        int beg = rp[n], end = rp[n + 1];
        float s[4] = {0.f, 0.f, 0.f, 0.f};
        if (s4) gather4_u8<4>(pm1 + goff, 0, pk, beg, end, s);
        else gather4_u8<8>(pm1 + goff, c0, pk, beg, end, s);
        size_t base = goff + (size_t)n * S + c0;
        float t[4];
        if (rec) {
            const float4 pv = *reinterpret_cast<const float4*>(pm2 + base);
            t[0] = 2.f * s[0] - pv.x; t[1] = 2.f * s[1] - pv.y;
            t[2] = 2.f * s[2] - pv.z; t[3] = 2.f * s[3] - pv.w;
        } else {
            t[0] = s[0]; t[1] = s[1]; t[2] = s[2]; t[3] = s[3];
        }
        *reinterpret_cast<float4*>(tx + base) = make_float4(t[0], t[1], t[2], t[3]);
    }
}

// ==================== batched deferred matmul ====================
// acc(n,:) += sum over k in [k0, k0+nk) of chain(tx_k(n,:), Wk) — per k:
// m = ascending-ci fmaf chain; acc = acc + m (ascending k). Register acc,
// one load + one store per batch: values identical to per-step rmw.
template <int LAYER>  // 2 -> accB (addrB), 3 -> accC (row 28)
__global__ __launch_bounds__(256) void mm_batch_kernel(
    const float* __restrict__ ring, int k0, int nk,
    const float* __restrict__ W, float* __restrict__ acc) {
#pragma clang fp contract(off)
    {
        constexpr int CIN = (LAYER == 2) ? 14 : 20;
        constexpr int COUT = (LAYER == 2) ? 20 : 27;
        int n = blockIdx.x * 256 + threadIdx.x;
        if (n >= N_NODES) return;
        float a[COUT];
        if constexpr (LAYER == 2) {
            const float4 v0 = *reinterpret_cast<const float4*>(acc + (size_t)n * 8);
            const float4 v1 = *reinterpret_cast<const float4*>(acc + (size_t)n * 8 + 4);
            const float4 v2 = *reinterpret_cast<const float4*>(acc + OFF1 + (size_t)n * 8);
            const float4 v3 = *reinterpret_cast<const float4*>(acc + OFF1 + (size_t)n * 8 + 4);
            const float4 v4 = *reinterpret_cast<const float4*>(acc + OFF2 + (size_t)n * 4);
            a[0] = v0.x; a[1] = v0.y; a[2] = v0.z; a[3] = v0.w;
            a[4] = v1.x; a[5] = v1.y; a[6] = v1.z; a[7] = v1.w;
            a[8] = v2.x; a[9] = v2.y; a[10] = v2.z; a[11] = v2.w;
            a[12] = v3.x; a[13] = v3.y; a[14] = v3.z; a[15] = v3.w;
            a[16] = v4.x; a[17] = v4.y; a[18] = v4.z; a[19] = v4.w;
        } else {
#pragma unroll
            for (int i = 0; i < 7; ++i) {
                const float4 v = *reinterpret_cast<const float4*>(acc + (size_t)n * 28 + i * 4);
                if (i * 4 + 0 < 27) a[i * 4 + 0] = v.x;
                if (i * 4 + 1 < 27) a[i * 4 + 1] = v.y;
                if (i * 4 + 2 < 27) a[i * 4 + 2] = v.z;
                if (i * 4 + 3 < 27) a[i * 4 + 3] = v.w;
            }
        }
        for (int kk = 0; kk < nk; ++kk) {
            int k = k0 + kk;
            const float* t = ring + (size_t)((k - 1) % 6) * SLOTF;
            float hv[CIN];
            if constexpr (LAYER == 2) {
                const float4 a0 = *reinterpret_cast<const float4*>(t + (size_t)n * 8);
                const float4 a1 = *reinterpret_cast<const float4*>(t + (size_t)n * 8 + 4);
                const float4 a2 = *reinterpret_cast<const float4*>(t + OFF1 + (size_t)n * 8);
                const float4 a3 = *reinterpret_cast<const float4*>(t + OFF1 + (size_t)n * 8 + 4);
                hv[0] = a0.x; hv[1] = a0.y; hv[2] = a0.z; hv[3] = a0.w;
                hv[4] = a1.x; hv[5] = a1.y; hv[6] = a1.z; hv[7] = a1.w;
                hv[8] = a2.x; hv[9] = a2.y; hv[10] = a2.z; hv[11] = a2.w;
                hv[12] = a3.x; hv[13] = a3.y;  // a3.z/.w are pads
            } else {
                const float4 a0 = *reinterpret_cast<const float4*>(t + (size_t)n * 8);
                const float4 a1 = *reinterpret_cast<const float4*>(t + (size_t)n * 8 + 4);
                const float4 a2 = *reinterpret_cast<const float4*>(t + OFF1 + (size_t)n * 8);
                const float4 a3 = *reinterpret_cast<const float4*>(t + OFF1 + (size_t)n * 8 + 4);
                const float4 a4 = *reinterpret_cast<const float4*>(t + OFF2 + (size_t)n * 4);
                hv[0] = a0.x; hv[1] = a0.y; hv[2] = a0.z; hv[3] = a0.w;
                hv[4] = a1.x; hv[5] = a1.y; hv[6] = a1.z; hv[7] = a1.w;
                hv[8] = a2.x; hv[9] = a2.y; hv[10] = a2.z; hv[11] = a2.w;
                hv[12] = a3.x; hv[13] = a3.y; hv[14] = a3.z; hv[15] = a3.w;
                hv[16] = a4.x; hv[17] = a4.y; hv[18] = a4.z; hv[19] = a4.w;
            }
            const float* Wk = W + (size_t)k * CIN * COUT;
            for (int co = 0; co < COUT; ++co) {
                float m = 0.f;
#pragma unroll
                for (int ci = 0; ci < CIN; ++ci) m = fmaf(hv[ci], Wk[ci * COUT + co], m);
                a[co] = a[co] + m;
            }
        }
        if constexpr (LAYER == 2) {
            *reinterpret_cast<float4*>(acc + (size_t)n * 8) = make_float4(a[0], a[1], a[2], a[3]);
            *reinterpret_cast<float4*>(acc + (size_t)n * 8 + 4) = make_float4(a[4], a[5], a[6], a[7]);
            *reinterpret_cast<float4*>(acc + OFF1 + (size_t)n * 8) = make_float4(a[8], a[9], a[10], a[11]);
            *reinterpret_cast<float4*>(acc + OFF1 + (size_t)n * 8 + 4) = make_float4(a[12], a[13], a[14], a[15]);
            *reinterpret_cast<float4*>(acc + OFF2 + (size_t)n * 4) = make_float4(a[16], a[17], a[18], a[19]);
        } else {
            for (int co = 0; co < 27; ++co) acc[(size_t)n * 28 + co] = a[co];
        }
    }
}

// acc(n,co) = chain(hin(n,:), W0) — split-layout aware (assign)
template <int LAYER>
__global__ void layer_init_kernel(const float* __restrict__ hin, const float* __restrict__ W0,
                                  float* __restrict__ acc) {
#pragma clang fp contract(off)
    {
        constexpr int CIN = (LAYER == 1) ? 2 : ((LAYER == 2) ? 14 : 20);
        constexpr int COUT = (LAYER == 1) ? 14 : ((LAYER == 2) ? 20 : 27);
        int t = blockIdx.x * blockDim.x + threadIdx.x;
        if (t >= N_NODES * COUT) return;
        int n = t / COUT, co = t - n * COUT;
        float m = 0.f;
#pragma unroll
        for (int ci = 0; ci < CIN; ++ci) {
            float hv;
            if constexpr (LAYER == 1) hv = hin[(size_t)n * 2 + ci];
            else if constexpr (LAYER == 2) hv = hin[addrA(n, ci)];
            else hv = hin[addrB(n, ci)];
            m = fmaf(hv, W0[ci * COUT + co], m);
        }
        size_t a;
        if constexpr (LAYER == 1) a = addrA(n, co);
        else if constexpr (LAYER == 2) a = addrB(n, co);
        else a = (size_t)n * 28 + co;
        acc[a] = m;
    }
}

// a = silu(a + b) over real channels of the split layout
template <int LAYER>
__global__ void silu_bias_kernel(float* __restrict__ a, const float* __restrict__ b) {
#pragma clang fp contract(off)
    {
        constexpr int C = (LAYER == 1) ? 14 : 20;
        int t = blockIdx.x * blockDim.x + threadIdx.x;
        if (t >= N_NODES * C) return;
        int n = t / C, c = t - n * C;
        size_t ad = (LAYER == 1) ? addrA(n, c) : addrB(n, c);
        float x = a[ad] + b[c];
        float sig = 1.f / (1.f + expf(-x));
        a[ad] = x * sig;
    }
}

// fused: silu(acc+b3) -> W4 dot -> sigmoid
__global__ void final_kernel(const float* __restrict__ acc, const float* __restrict__ b3,
                             const float* __restrict__ W4, float* __restrict__ out) {
#pragma clang fp contract(off)
    {
        int n = blockIdx.x * blockDim.x + threadIdx.x;
        if (n >= N_NODES) return;
        float m = 0.f;
#pragma unroll
        for (int ci = 0; ci < 27; ++ci) {
            float xv = acc[(size_t)n * 28 + ci] + b3[ci];
            float sig = 1.f / (1.f + expf(-xv));
            float hv = xv * sig;
            m = fmaf(hv, W4[ci], m);
        }
        out[n] = 1.f / (1.f + expf(-m));
    }
}

__global__ void signal_kernel(float* __restrict__ out, float val) {
    int n = blockIdx.x * blockDim.x + threadIdx.x;
    if (n < N_NODES) out[n] = val;
}

// ==================== host driver ====================

static void run_scan(const int* cnt, int* bsums, int* rp, hipStream_t stream) {
    const int nb = (N_NODES + 1023) / 1024;  // 98
    scan_partial_kernel<<<nb, 256, 0, stream>>>(cnt, bsums);
    scan_bsums_kernel<<<1, 64, 0, stream>>>(bsums, nb, rp + N_NODES);
    scan_final_kernel<<<nb, 256, 0, stream>>>(cnt, bsums, rp);
}

extern "C" void kernel_launch(void* const* d_in, const int* in_sizes, int n_in, void* d_out,
                              int out_size, void* d_ws, size_t ws_size, hipStream_t stream) {
    const float* x  = (const float*)d_in[0];
    const int* idx  = (const int*)d_in[1];
    const float* ew = (const float*)d_in[2];
    const float* W1 = (const float*)d_in[3];
    const float* b1 = (const float*)d_in[4];
    const float* W2 = (const float*)d_in[5];
    const float* b2 = (const float*)d_in[6];
    const float* W3 = (const float*)d_in[7];
    const float* b3 = (const float*)d_in[8];
    const float* W4 = (const float*)d_in[9];
    float* out = (float*)d_out;
    (void)in_sizes; (void)n_in; (void)out_size;

    const int* src = idx;
    const int* dst = idx + N_EDGES;

    // workspace carve-up (256B aligned) — ~204 MB (budget ~272 MB)
    size_t off = 0;
    auto alloc = [&](size_t bytes) {
        size_t o = off;
        off = (off + bytes + 255) & ~(size_t)255;
        return o;
    };
    char* ws = (char*)d_ws;
    int*   cnt_s   = (int*)(ws + alloc(N_NODES * 4));
    int*   cnt_d   = (int*)(ws + alloc(N_NODES * 4));
    int*   rp_src  = (int*)(ws + alloc((N_NODES + 1) * 4));
    int*   rp_dst  = (int*)(ws + alloc((N_NODES + 1) * 4));
    float* dis     = (float*)(ws + alloc(N_NODES * 4));
    int*   bsums   = (int*)(ws + alloc(512));
    int2*  packed  = (int2*)(ws + alloc((size_t)N_EDGES * 8));       // 25.6MB
    float* ring    = (float*)(ws + alloc((size_t)6 * SLOTF * 4));    // 48MB tx ring
    float* accA    = (float*)(ws + alloc((size_t)1600000 * 4));      // L1 out {8|6+2pad} 6.4MB
    float* accB    = (float*)(ws + alloc((size_t)2000000 * 4));      // L2 out {8|8|4} 8MB
    float* accC    = (float*)(ws + alloc((size_t)N_NODES * 28 * 4)); // L3 out row28 11.2MB
    int*   bkt_s   = (int*)(ws + alloc((size_t)N_NODES * CAP * 4));  // 51.2MB
    int*   bkt_d   = (int*)(ws + alloc((size_t)N_NODES * CAP * 4));  // 51.2MB
    const size_t NEED = off;

    int gE = (N_EDGES + BS - 1) / BS;
    int gN = (N_NODES + BS - 1) / BS;
    const int gSort = (N_NODES + 63) / 64;

    if (ws_size < NEED) {
        signal_kernel<<<gN, BS, 0, stream>>>(
            out, 6000.0f + (float)(ws_size / (1024.0 * 1024.0)));
        return;
    }

    // ---- setup (r19-verbatim) ----
    (void)hipMemsetAsync(cnt_s, 0, N_NODES * 4, stream);
    (void)hipMemsetAsync(cnt_d, 0, N_NODES * 4, stream);
    fill_direct_kernel<<<gE, BS, 0, stream>>>(src, dst, cnt_s, cnt_d, bkt_s, bkt_d);
    run_scan(cnt_s, bsums, rp_src, stream);
    run_scan(cnt_d, bsums, rp_dst, stream);
    sort_deg_dis_kernel<<<gSort, 64, 0, stream>>>(cnt_s, bkt_s, ew, dis);
    sort_pack_kernel<<<gSort, 64, 0, stream>>>(cnt_d, rp_dst, bkt_d, src, ew, dis, packed);

    // accA pads (ch14,15) must be 0 (gathered by L2 props; stay 0 thereafter)
    (void)hipMemsetAsync(accA, 0, (size_t)1600000 * 4, stream);

    // ---- L1: fused (state 0.8MB, L2-resident everywhere), K=39 ----
    layer_init_kernel<1><<<(N_NODES * 14 + BS - 1) / BS, BS, 0, stream>>>(x, W1, accA);
    {
        const float* pm1 = x;
        const float* pm2 = nullptr;
        for (int k = 1; k < 39; ++k) {
            float* txk = ring + (size_t)((k - 1) % 3) * SLOTF;
            prop_l1_kernel<<<391, 256, 0, stream>>>(rp_dst, packed, pm1, pm2,
                                                    W1 + (size_t)k * 2 * 14, (k >= 2) ? 1 : 0,
                                                    txk, accA);
            pm2 = pm1;
            pm1 = txk;
        }
    }
    silu_bias_kernel<1><<<(N_NODES * 14 + BS - 1) / BS, BS, 0, stream>>>(accA, b1);

    // ---- L2: XCD-split props + batched mm, K=43 ----
    layer_init_kernel<2><<<(N_NODES * 20 + BS - 1) / BS, BS, 0, stream>>>(accA, W2, accB);
    {
        int last = 0;
        for (int k = 1; k < 43; ++k) {
            const float* pm1 = (k == 1) ? accA : ring + (size_t)((k - 2) % 6) * SLOTF;
            const float* pm2 = (k == 2) ? accA
                             : ((k >= 3) ? ring + (size_t)((k - 3) % 6) * SLOTF : nullptr);
            prop_split_kernel<2><<<1564, 256, 0, stream>>>(
                rp_dst, packed, pm1, pm2, ring + (size_t)((k - 1) % 6) * SLOTF, (k >= 2) ? 1 : 0);
            if (k - last == 4 || k == 42) {
                mm_batch_kernel<2><<<391, 256, 0, stream>>>(ring, last + 1, k - last, W2, accB);
                last = k;
            }
        }
    }
    silu_bias_kernel<2><<<(N_NODES * 20 + BS - 1) / BS, BS, 0, stream>>>(accB, b2);

    // ---- L3: XCD-split props + batched mm, K=45 ----
    layer_init_kernel<3><<<(N_NODES * 27 + BS - 1) / BS, BS, 0, stream>>>(accB, W3, accC);
    {
        int last = 0;
        for (int k = 1; k < 45; ++k) {
            const float* pm1 = (k == 1) ? accB : ring + (size_t)((k - 2) % 6) * SLOTF;
            const float* pm2 = (k == 2) ? accB
                             : ((k >= 3) ? ring + (size_t)((k - 3) % 6) * SLOTF : nullptr);
            prop_split_kernel<3><<<2088, 256, 0, stream>>>(
                rp_dst, packed, pm1, pm2, ring + (size_t)((k - 1) % 6) * SLOTF, (k >= 2) ? 1 : 0);
            if (k - last == 4 || k == 44) {
                mm_batch_kernel<3><<<391, 256, 0, stream>>>(ring, last + 1, k - last, W3, accC);
                last = k;
            }
        }
    }
    final_kernel<<<gN, BS, 0, stream>>>(accC, b3, W4, out);
}

// Round 11
// 7899.191 us; speedup vs baseline: 1.1423x; 1.1423x over previous
//
// r22 = r19 (best passing, 7684us) + L1 prop occupancy fix: LANES=2 channel
// split (1 thread/node -> 2), scalar gathers, chains byte-identical.
// Ledger: r14 8148 | r16 seq-groups -37% | r17 phased-fill null | r18 -2.3x |
// r19 7684 | r21 XCD-split 9023 (theory refuted, line CLOSED).
#include <hip/hip_runtime.h>
#include <math.h>

#define N_NODES 100000
#define N_EDGES 3200000
#define BS 256
#define CAP_SHIFT 7            // 128 bucket slots per node; max deg ~59
#define CAP (1 << CAP_SHIFT)

// ==================== deterministic all-f32 data path ====================
// Rounding-matched to numpy (absmax 0 at r14/r16/r17/r19/r21):
//  - bucket sums in ascending edge-id order; SpMV products rounded then added
//  - matmuls ascending-ci fmaf chains from 0; acc adds ascending k
//  - dis = 1/sqrtf. ONLY ADDRESSES / lane assignments may change.

__global__ void scan_partial_kernel(const int* __restrict__ cnt, int* __restrict__ bsums) {
    __shared__ int lds[256];
    int tid = threadIdx.x;
    int base = blockIdx.x * 1024 + tid * 4;
    int s = 0;
#pragma unroll
    for (int i = 0; i < 4; ++i) s += (base + i < N_NODES) ? cnt[base + i] : 0;
    lds[tid] = s;
    __syncthreads();
    for (int off = 128; off > 0; off >>= 1) {
        if (tid < off) lds[tid] += lds[tid + off];
        __syncthreads();
    }
    if (tid == 0) bsums[blockIdx.x] = lds[0];
}

__global__ void scan_bsums_kernel(int* __restrict__ bsums, int nb, int* __restrict__ total_out) {
    if (threadIdx.x == 0 && blockIdx.x == 0) {
        int acc = 0;
        for (int b = 0; b < nb; ++b) {
            int v = bsums[b];
            bsums[b] = acc;
            acc += v;
        }
        *total_out = acc;
    }
}

__global__ void scan_final_kernel(const int* __restrict__ cnt, const int* __restrict__ bsums,
                                  int* __restrict__ rp) {
    __shared__ int lds[256];
    int tid = threadIdx.x;
    int base = blockIdx.x * 1024 + tid * 4;
    int v[4];
    int ts = 0;
#pragma unroll
    for (int i = 0; i < 4; ++i) {
        v[i] = (base + i < N_NODES) ? cnt[base + i] : 0;
        ts += v[i];
    }
    lds[tid] = ts;
    __syncthreads();
    for (int off = 1; off < 256; off <<= 1) {
        int t = (tid >= off) ? lds[tid - off] : 0;
        __syncthreads();
        lds[tid] += t;
        __syncthreads();
    }
    int run = lds[tid] - ts + bsums[blockIdx.x];
#pragma unroll
    for (int i = 0; i < 4; ++i) {
        if (base + i < N_NODES) rp[base + i] = run;
        run += v[i];
    }
}

__global__ void fill_direct_kernel(const int* __restrict__ src, const int* __restrict__ dst,
                                   int* __restrict__ cnt_s, int* __restrict__ cnt_d,
                                   int* __restrict__ bkt_s, int* __restrict__ bkt_d) {
    int e = blockIdx.x * blockDim.x + threadIdx.x;
    if (e >= N_EDGES) return;
    int s = src[e];
    int d = dst[e];
    int slot_s = atomicAdd(&cnt_s[s], 1);
    bkt_s[((size_t)s << CAP_SHIFT) + slot_s] = e;
    int slot_d = atomicAdd(&cnt_d[d], 1);
    bkt_d[((size_t)d << CAP_SHIFT) + slot_d] = e;
}

// src-side: LDS-staged rank-sort by edge id, then ordered deg sum -> dis.
__global__ __launch_bounds__(64) void sort_deg_dis_kernel(
    const int* __restrict__ cnt, const int* __restrict__ bkt,
    const float* __restrict__ w, float* __restrict__ dis) {
#pragma clang fp contract(off)
    {
        __shared__ int lr[64][65];
        __shared__ int ls[64][65];
        int n = blockIdx.x * 64 + threadIdx.x;
        if (n >= N_NODES) return;
        int c = cnt[n];
        const int* row = bkt + ((size_t)n << CAP_SHIFT);
        float d = 0.f;
        if (c <= 64) {
            int* a = lr[threadIdx.x];
            int* b = ls[threadIdx.x];
            for (int i = 0; i < c; ++i) a[i] = row[i];
            for (int i = 0; i < c; ++i) {
                int v = a[i];
                int rk = 0;
                for (int j = 0; j < c; ++j) rk += (a[j] < v);
                b[rk] = v;
            }
            for (int r = 0; r < c; ++r) d = d + w[b[r]];
        } else {
            for (int r = 0; r < c; ++r) {
                for (int i = 0; i < c; ++i) {
                    int v = row[i];
                    int rk = 0;
                    for (int j = 0; j < c; ++j) rk += (row[j] < v);
                    if (rk == r) { d = d + w[v]; break; }
                }
            }
        }
        dis[n] = (d > 0.f) ? (1.0f / sqrtf(d)) : 0.f;
    }
}

// dst-side: LDS-staged rank-sort, emit packed[beg+r] = {src, ((-dis[s])*w)*dis[n]}.
__global__ __launch_bounds__(64) void sort_pack_kernel(
    const int* __restrict__ cnt, const int* __restrict__ rp,
    const int* __restrict__ bkt, const int* __restrict__ src,
    const float* __restrict__ w, const float* __restrict__ dis,
    int2* __restrict__ packed) {
#pragma clang fp contract(off)
    {
        __shared__ int lr[64][65];
        __shared__ int ls[64][65];
        int n = blockIdx.x * 64 + threadIdx.x;
        if (n >= N_NODES) return;
        int c = cnt[n];
        const int* row = bkt + ((size_t)n << CAP_SHIFT);
        int beg = rp[n];
        float din = dis[n];
        if (c <= 64) {
            int* a = lr[threadIdx.x];
            int* b = ls[threadIdx.x];
            for (int i = 0; i < c; ++i) a[i] = row[i];
            for (int i = 0; i < c; ++i) {
                int v = a[i];
                int rk = 0;
                for (int j = 0; j < c; ++j) rk += (a[j] < v);
                b[rk] = v;
            }
            for (int r = 0; r < c; ++r) {
                int e = b[r];
                int s = src[e];
                float cw = ((-dis[s]) * w[e]) * din;
                packed[beg + r] = make_int2(s, __float_as_int(cw));
            }
        } else {
            for (int r = 0; r < c; ++r) {
                for (int i = 0; i < c; ++i) {
                    int v = row[i];
                    int rk = 0;
                    for (int j = 0; j < c; ++j) rk += (row[j] < v);
                    if (rk == r) {
                        int s = src[v];
                        float cw = ((-dis[s]) * w[v]) * din;
                        packed[beg + r] = make_int2(s, __float_as_int(cw));
                        break;
                    }
                }
            }
        }
    }
}

// ==================== per-layer kernels (r14/r19 structure) ====================

template <int CIN, int COUT, int SIN, int SACC>
__global__ void layer_init_kernel(const float* __restrict__ hin, const float* __restrict__ W0,
                                  float* __restrict__ acc) {
    int t = blockIdx.x * blockDim.x + threadIdx.x;
    if (t >= N_NODES * COUT) return;
    int n = t / COUT, co = t - n * COUT;
    const float* hr = hin + (size_t)n * SIN;
    float m = 0.f;
#pragma unroll
    for (int ci = 0; ci < CIN; ++ci) m = fmaf(hr[ci], W0[ci * COUT + co], m);
    acc[(size_t)n * SACC + co] = m;
}

// Grouped-channel prop+matmul. Block = R rows x LANES lanes; lane owns GS
// consecutive channels (GS=4 float4, GS=2 float2, GS=1 scalar). Per-channel
// gather chains in ascending edge-id order (mul rounded then add); recurrence;
// LDS handoff; ascending-ci fmaf matmul chain; acc += m. Edge loop unroll x8.
template <int CIN, int COUT, int SIN, int SACC, int GS, int LANES, int R>
__global__ __launch_bounds__(LANES* R) void prop_mm_kernel(
    const int* __restrict__ rp, const int2* __restrict__ pk, const float* __restrict__ hin,
    const float* __restrict__ prev, const float* __restrict__ Wk, int rec,
    float* __restrict__ tx_out, float* __restrict__ acc) {
#pragma clang fp contract(off)
    {
        __shared__ float tls[R][LANES * GS];
        int r = threadIdx.x / LANES;
        int lane = threadIdx.x - r * LANES;
        int n = blockIdx.x * R + r;
        bool vn = (n < N_NODES);
        if (vn) {
            int c0 = lane * GS;
            float s[GS];
#pragma unroll
            for (int g = 0; g < GS; ++g) s[g] = 0.f;
            int beg = rp[n], end = rp[n + 1];
            int j = beg;
            if constexpr (GS == 4) {
                for (; j + 7 < end; j += 8) {
                    int2 p0 = pk[j];
                    int2 p1 = pk[j + 1];
                    int2 p2 = pk[j + 2];
                    int2 p3 = pk[j + 3];
                    int2 p4 = pk[j + 4];
                    int2 p5 = pk[j + 5];
                    int2 p6 = pk[j + 6];
                    int2 p7 = pk[j + 7];
                    const float4 q0 = *reinterpret_cast<const float4*>(hin + (size_t)p0.x * SIN + c0);
                    const float4 q1 = *reinterpret_cast<const float4*>(hin + (size_t)p1.x * SIN + c0);
                    const float4 q2 = *reinterpret_cast<const float4*>(hin + (size_t)p2.x * SIN + c0);
                    const float4 q3 = *reinterpret_cast<const float4*>(hin + (size_t)p3.x * SIN + c0);
                    const float4 q4 = *reinterpret_cast<const float4*>(hin + (size_t)p4.x * SIN + c0);
                    const float4 q5 = *reinterpret_cast<const float4*>(hin + (size_t)p5.x * SIN + c0);
                    const float4 q6 = *reinterpret_cast<const float4*>(hin + (size_t)p6.x * SIN + c0);
                    const float4 q7 = *reinterpret_cast<const float4*>(hin + (size_t)p7.x * SIN + c0);
                    float w0 = __int_as_float(p0.y), w1 = __int_as_float(p1.y);
                    float w2 = __int_as_float(p2.y), w3 = __int_as_float(p3.y);
                    float w4 = __int_as_float(p4.y), w5 = __int_as_float(p5.y);
                    float w6 = __int_as_float(p6.y), w7 = __int_as_float(p7.y);
                    s[0] = s[0] + (w0 * q0.x); s[1] = s[1] + (w0 * q0.y);
                    s[2] = s[2] + (w0 * q0.z); s[3] = s[3] + (w0 * q0.w);
                    s[0] = s[0] + (w1 * q1.x); s[1] = s[1] + (w1 * q1.y);
                    s[2] = s[2] + (w1 * q1.z); s[3] = s[3] + (w1 * q1.w);
                    s[0] = s[0] + (w2 * q2.x); s[1] = s[1] + (w2 * q2.y);
                    s[2] = s[2] + (w2 * q2.z); s[3] = s[3] + (w2 * q2.w);
                    s[0] = s[0] + (w3 * q3.x); s[1] = s[1] + (w3 * q3.y);
                    s[2] = s[2] + (w3 * q3.z); s[3] = s[3] + (w3 * q3.w);
                    s[0] = s[0] + (w4 * q4.x); s[1] = s[1] + (w4 * q4.y);
                    s[2] = s[2] + (w4 * q4.z); s[3] = s[3] + (w4 * q4.w);
                    s[0] = s[0] + (w5 * q5.x); s[1] = s[1] + (w5 * q5.y);
                    s[2] = s[2] + (w5 * q5.z); s[3] = s[3] + (w5 * q5.w);
                    s[0] = s[0] + (w6 * q6.x); s[1] = s[1] + (w6 * q6.y);
                    s[2] = s[2] + (w6 * q6.z); s[3] = s[3] + (w6 * q6.w);
                    s[0] = s[0] + (w7 * q7.x); s[1] = s[1] + (w7 * q7.y);
                    s[2] = s[2] + (w7 * q7.z); s[3] = s[3] + (w7 * q7.w);
                }
                for (; j + 3 < end; j += 4) {
                    int2 p0 = pk[j];
                    int2 p1 = pk[j + 1];
                    int2 p2 = pk[j + 2];
                    int2 p3 = pk[j + 3];
                    const float4 q0 = *reinterpret_cast<const float4*>(hin + (size_t)p0.x * SIN + c0);
                    const float4 q1 = *reinterpret_cast<const float4*>(hin + (size_t)p1.x * SIN + c0);
                    const float4 q2 = *reinterpret_cast<const float4*>(hin + (size_t)p2.x * SIN + c0);
                    const float4 q3 = *reinterpret_cast<const float4*>(hin + (size_t)p3.x * SIN + c0);
                    float w0 = __int_as_float(p0.y), w1 = __int_as_float(p1.y);
                    float w2 = __int_as_float(p2.y), w3 = __int_as_float(p3.y);
                    s[0] = s[0] + (w0 * q0.x); s[1] = s[1] + (w0 * q0.y);
                    s[2] = s[2] + (w0 * q0.z); s[3] = s[3] + (w0 * q0.w);
                    s[0] = s[0] + (w1 * q1.x); s[1] = s[1] + (w1 * q1.y);
                    s[2] = s[2] + (w1 * q1.z); s[3] = s[3] + (w1 * q1.w);
                    s[0] = s[0] + (w2 * q2.x); s[1] = s[1] + (w2 * q2.y);
                    s[2] = s[2] + (w2 * q2.z); s[3] = s[3] + (w2 * q2.w);
                    s[0] = s[0] + (w3 * q3.x); s[1] = s[1] + (w3 * q3.y);
                    s[2] = s[2] + (w3 * q3.z); s[3] = s[3] + (w3 * q3.w);
                }
                for (; j < end; ++j) {
                    int2 p = pk[j];
                    float w = __int_as_float(p.y);
                    const float4 q = *reinterpret_cast<const float4*>(hin + (size_t)p.x * SIN + c0);
                    s[0] = s[0] + (w * q.x); s[1] = s[1] + (w * q.y);
                    s[2] = s[2] + (w * q.z); s[3] = s[3] + (w * q.w);
                }
            } else if constexpr (GS == 2) {
                for (; j + 7 < end; j += 8) {
                    int2 p0 = pk[j];
                    int2 p1 = pk[j + 1];
                    int2 p2 = pk[j + 2];
                    int2 p3 = pk[j + 3];
                    int2 p4 = pk[j + 4];
                    int2 p5 = pk[j + 5];
                    int2 p6 = pk[j + 6];
                    int2 p7 = pk[j + 7];
                    const float2 q0 = *reinterpret_cast<const float2*>(hin + (size_t)p0.x * SIN + c0);
                    const float2 q1 = *reinterpret_cast<const float2*>(hin + (size_t)p1.x * SIN + c0);
                    const float2 q2 = *reinterpret_cast<const float2*>(hin + (size_t)p2.x * SIN + c0);
                    const float2 q3 = *reinterpret_cast<const float2*>(hin + (size_t)p3.x * SIN + c0);
                    const float2 q4 = *reinterpret_cast<const float2*>(hin + (size_t)p4.x * SIN + c0);
                    const float2 q5 = *reinterpret_cast<const float2*>(hin + (size_t)p5.x * SIN + c0);
                    const float2 q6 = *reinterpret_cast<const float2*>(hin + (size_t)p6.x * SIN + c0);
                    const float2 q7 = *reinterpret_cast<const float2*>(hin + (size_t)p7.x * SIN + c0);
                    float w0 = __int_as_float(p0.y), w1 = __int_as_float(p1.y);
                    float w2 = __int_as_float(p2.y), w3 = __int_as_float(p3.y);
                    float w4 = __int_as_float(p4.y), w5 = __int_as_float(p5.y);
                    float w6 = __int_as_float(p6.y), w7 = __int_as_float(p7.y);
                    s[0] = s[0] + (w0 * q0.x); s[1] = s[1] + (w0 * q0.y);
                    s[0] = s[0] + (w1 * q1.x); s[1] = s[1] + (w1 * q1.y);
                    s[0] = s[0] + (w2 * q2.x); s[1] = s[1] + (w2 * q2.y);
                    s[0] = s[0] + (w3 * q3.x); s[1] = s[1] + (w3 * q3.y);
                    s[0] = s[0] + (w4 * q4.x); s[1] = s[1] + (w4 * q4.y);
                    s[0] = s[0] + (w5 * q5.x); s[1] = s[1] + (w5 * q5.y);
                    s[0] = s[0] + (w6 * q6.x); s[1] = s[1] + (w6 * q6.y);
                    s[0] = s[0] + (w7 * q7.x); s[1] = s[1] + (w7 * q7.y);
                }
                for (; j + 3 < end; j += 4) {
                    int2 p0 = pk[j];
                    int2 p1 = pk[j + 1];
                    int2 p2 = pk[j + 2];
                    int2 p3 = pk[j + 3];
                    const float2 q0 = *reinterpret_cast<const float2*>(hin + (size_t)p0.x * SIN + c0);
                    const float2 q1 = *reinterpret_cast<const float2*>(hin + (size_t)p1.x * SIN + c0);
                    const float2 q2 = *reinterpret_cast<const float2*>(hin + (size_t)p2.x * SIN + c0);
                    const float2 q3 = *reinterpret_cast<const float2*>(hin + (size_t)p3.x * SIN + c0);
                    float w0 = __int_as_float(p0.y), w1 = __int_as_float(p1.y);
                    float w2 = __int_as_float(p2.y), w3 = __int_as_float(p3.y);
                    s[0] = s[0] + (w0 * q0.x); s[1] = s[1] + (w0 * q0.y);
                    s[0] = s[0] + (w1 * q1.x); s[1] = s[1] + (w1 * q1.y);
                    s[0] = s[0] + (w2 * q2.x); s[1] = s[1] + (w2 * q2.y);
                    s[0] = s[0] + (w3 * q3.x); s[1] = s[1] + (w3 * q3.y);
                }
                for (; j < end; ++j) {
                    int2 p = pk[j];
                    float w = __int_as_float(p.y);
                    const float2 q = *reinterpret_cast<const float2*>(hin + (size_t)p.x * SIN + c0);
                    s[0] = s[0] + (w * q.x); s[1] = s[1] + (w * q.y);
                }
            } else {  // GS == 1: scalar gather (L1 channel-split; lanes of a
                      // node read adjacent words -> coalesced to one segment)
                for (; j + 7 < end; j += 8) {
                    int2 p0 = pk[j];
                    int2 p1 = pk[j + 1];
                    int2 p2 = pk[j + 2];
                    int2 p3 = pk[j + 3];
                    int2 p4 = pk[j + 4];
                    int2 p5 = pk[j + 5];
                    int2 p6 = pk[j + 6];
                    int2 p7 = pk[j + 7];
                    float q0 = hin[(size_t)p0.x * SIN + c0];
                    float q1 = hin[(size_t)p1.x * SIN + c0];
                    float q2 = hin[(size_t)p2.x * SIN + c0];
                    float q3 = hin[(size_t)p3.x * SIN + c0];
                    float q4 = hin[(size_t)p4.x * SIN + c0];
                    float q5 = hin[(size_t)p5.x * SIN + c0];
                    float q6 = hin[(size_t)p6.x * SIN + c0];
                    float q7 = hin[(size_t)p7.x * SIN + c0];
                    float w0 = __int_as_float(p0.y), w1 = __int_as_float(p1.y);
                    float w2 = __int_as_float(p2.y), w3 = __int_as_float(p3.y);
                    float w4 = __int_as_float(p4.y), w5 = __int_as_float(p5.y);
                    float w6 = __int_as_float(p6.y), w7 = __int_as_float(p7.y);
                    s[0] = s[0] + (w0 * q0);
                    s[0] = s[0] + (w1 * q1);
                    s[0] = s[0] + (w2 * q2);
                    s[0] = s[0] + (w3 * q3);
                    s[0] = s[0] + (w4 * q4);
                    s[0] = s[0] + (w5 * q5);
                    s[0] = s[0] + (w6 * q6);
                    s[0] = s[0] + (w7 * q7);
                }
                for (; j < end; ++j) {
                    int2 p = pk[j];
                    float w = __int_as_float(p.y);
                    float q = hin[(size_t)p.x * SIN + c0];
                    s[0] = s[0] + (w * q);
                }
            }
            float t[GS];
            if (rec) {
#pragma unroll
                for (int g = 0; g < GS; ++g) t[g] = 2.f * s[g] - prev[(size_t)n * SIN + c0 + g];
            } else {
#pragma unroll
                for (int g = 0; g < GS; ++g) t[g] = s[g];
            }
#pragma unroll
            for (int g = 0; g < GS; ++g) tls[r][c0 + g] = t[g];
            if constexpr (GS == 4) {
                *reinterpret_cast<float4*>(tx_out + (size_t)n * SIN + c0) =
                    make_float4(t[0], t[1], t[2], t[3]);
            } else if constexpr (GS == 2) {
                *reinterpret_cast<float2*>(tx_out + (size_t)n * SIN + c0) =
                    make_float2(t[0], t[1]);
            } else {
                tx_out[(size_t)n * SIN + c0] = t[0];
            }
        }
        __syncthreads();
        if (vn) {
            for (int co = lane; co < COUT; co += LANES) {
                float m = 0.f;
#pragma unroll
                for (int ci = 0; ci < CIN; ++ci) m = fmaf(tls[r][ci], Wk[ci * COUT + co], m);
                acc[(size_t)n * SACC + co] = acc[(size_t)n * SACC + co] + m;
            }
        }
    }
}

// a = silu(a + b) at padded stride S, real channels C only
template <int C, int S>
__global__ void silu_bias_kernel(float* __restrict__ a, const float* __restrict__ b) {
#pragma clang fp contract(off)
    {
        int t = blockIdx.x * blockDim.x + threadIdx.x;
        if (t >= N_NODES * C) return;
        int n = t / C, c = t - n * C;
        float x = a[(size_t)n * S + c] + b[c];
        float sig = 1.f / (1.f + expf(-x));
        a[(size_t)n * S + c] = x * sig;
    }
}

// fused: silu(acc+b3) -> W4 dot -> sigmoid
__global__ void final_kernel(const float* __restrict__ acc, const float* __restrict__ b3,
                             const float* __restrict__ W4, float* __restrict__ out) {
#pragma clang fp contract(off)
    {
        int n = blockIdx.x * blockDim.x + threadIdx.x;
        if (n >= N_NODES) return;
        float m = 0.f;
#pragma unroll
        for (int ci = 0; ci < 27; ++ci) {
            float xv = acc[(size_t)n * 28 + ci] + b3[ci];
            float sig = 1.f / (1.f + expf(-xv));
            float hv = xv * sig;
            m = fmaf(hv, W4[ci], m);
        }
        out[n] = 1.f / (1.f + expf(-m));
    }
}

__global__ void signal_kernel(float* __restrict__ out, float val) {
    int n = blockIdx.x * blockDim.x + threadIdx.x;
    if (n < N_NODES) out[n] = val;
}

// ==================== host driver ====================

static void run_scan(const int* cnt, int* bsums, int* rp, hipStream_t stream) {
    const int nb = (N_NODES + 1023) / 1024;  // 98
    scan_partial_kernel<<<nb, 256, 0, stream>>>(cnt, bsums);
    scan_bsums_kernel<<<1, 64, 0, stream>>>(bsums, nb, rp + N_NODES);
    scan_final_kernel<<<nb, 256, 0, stream>>>(cnt, bsums, rp);
}

template <int CIN, int COUT, int SIN, int SACC, int GS, int LANES, int R>
static void run_layer(int K, const float* hin, const float* W, float* acc, float* b0, float* b1,
                      float* b2, const int* rp, const int2* pk, hipStream_t stream) {
    const int gInit = (N_NODES * COUT + BS - 1) / BS;
    const int gProp = (N_NODES + R - 1) / R;
    layer_init_kernel<CIN, COUT, SIN, SACC><<<gInit, BS, 0, stream>>>(hin, W, acc);
    if (K > 1) {
        float* bufs[3] = {b0, b1, b2};
        prop_mm_kernel<CIN, COUT, SIN, SACC, GS, LANES, R><<<gProp, LANES * R, 0, stream>>>(
            rp, pk, hin, nullptr, W + 1 * CIN * COUT, 0, bufs[0], acc);
        const float* pm2 = hin;      // tx_{k-2}
        const float* pm1 = bufs[0];  // tx_{k-1}
        for (int k = 2; k < K; ++k) {
            float* outb = bufs[(k - 1) % 3];  // k=2->b1, k=3->b2, k=4->b0, ...
            prop_mm_kernel<CIN, COUT, SIN, SACC, GS, LANES, R><<<gProp, LANES * R, 0, stream>>>(
                rp, pk, pm1, pm2, W + k * CIN * COUT, 1, outb, acc);
            pm2 = pm1;
            pm1 = outb;
        }
    }
}

extern "C" void kernel_launch(void* const* d_in, const int* in_sizes, int n_in, void* d_out,
                              int out_size, void* d_ws, size_t ws_size, hipStream_t stream) {
    const float* x  = (const float*)d_in[0];
    const int* idx  = (const int*)d_in[1];
    const float* ew = (const float*)d_in[2];
    const float* W1 = (const float*)d_in[3];
    const float* b1 = (const float*)d_in[4];
    const float* W2 = (const float*)d_in[5];
    const float* b2 = (const float*)d_in[6];
    const float* W3 = (const float*)d_in[7];
    const float* b3 = (const float*)d_in[8];
    const float* W4 = (const float*)d_in[9];
    float* out = (float*)d_out;
    (void)in_sizes; (void)n_in; (void)out_size;

    const int* src = idx;
    const int* dst = idx + N_EDGES;

    // workspace carve-up (256B aligned) — ~180 MB (budget ~272 MB)
    size_t off = 0;
    auto alloc = [&](size_t bytes) {
        size_t o = off;
        off = (off + bytes + 255) & ~(size_t)255;
        return o;
    };
    char* ws = (char*)d_ws;
    int*   cnt_s   = (int*)(ws + alloc(N_NODES * 4));          // fill cursors == counts
    int*   cnt_d   = (int*)(ws + alloc(N_NODES * 4));
    int*   rp_src  = (int*)(ws + alloc((N_NODES + 1) * 4));
    int*   rp_dst  = (int*)(ws + alloc((N_NODES + 1) * 4));
    float* dis     = (float*)(ws + alloc(N_NODES * 4));
    int*   bsums   = (int*)(ws + alloc(512));
    int2*  packed  = (int2*)(ws + alloc((size_t)N_EDGES * 8));     // 25.6MB
    float* t0      = (float*)(ws + alloc((size_t)N_NODES * 20 * 4));  // tx, stride<=20
    float* t1      = (float*)(ws + alloc((size_t)N_NODES * 20 * 4));
    float* t2      = (float*)(ws + alloc((size_t)N_NODES * 20 * 4));
    float* accA    = (float*)(ws + alloc((size_t)N_NODES * 16 * 4));  // L1 out, stride 16
    float* accB    = (float*)(ws + alloc((size_t)N_NODES * 20 * 4));  // L2 out, stride 20
    float* accC    = (float*)(ws + alloc((size_t)N_NODES * 28 * 4));  // L3 out, stride 28
    int*   bkt_s   = (int*)(ws + alloc((size_t)N_NODES * CAP * 4));   // 51.2MB
    int*   bkt_d   = (int*)(ws + alloc((size_t)N_NODES * CAP * 4));   // 51.2MB
    const size_t NEED = off;

    int gE = (N_EDGES + BS - 1) / BS;
    int gN = (N_NODES + BS - 1) / BS;
    const int gSort = (N_NODES + 63) / 64;

    if (ws_size < NEED) {  // diagnostic: reveal ws_size in MB via absmax
        signal_kernel<<<gN, BS, 0, stream>>>(
            out, 6000.0f + (float)(ws_size / (1024.0 * 1024.0)));
        return;
    }

    // ---- setup: fill, scans, fused sort+deg / sort+pack (r19-verbatim) ----
    (void)hipMemsetAsync(cnt_s, 0, N_NODES * 4, stream);
    (void)hipMemsetAsync(cnt_d, 0, N_NODES * 4, stream);
    fill_direct_kernel<<<gE, BS, 0, stream>>>(src, dst, cnt_s, cnt_d, bkt_s, bkt_d);
    run_scan(cnt_s, bsums, rp_src, stream);
    run_scan(cnt_d, bsums, rp_dst, stream);
    sort_deg_dis_kernel<<<gSort, 64, 0, stream>>>(cnt_s, bkt_s, ew, dis);
    sort_pack_kernel<<<gSort, 64, 0, stream>>>(cnt_d, rp_dst, bkt_d, src, ew, dis, packed);

    // ---- layers ----
    // L1: CIN=2 (x, stride 2), out accA stride 16; 2 lanes x 128 rows
    // (channel-split scalar gathers -> 2x waves vs r19's 1x256; chains identical)
    run_layer<2, 14, 2, 16, 1, 2, 128>(39, x, W1, accA, t0, t1, t2, rp_dst, packed, stream);
    silu_bias_kernel<14, 16><<<(N_NODES * 14 + BS - 1) / BS, BS, 0, stream>>>(accA, b1);
    // L2: CIN=14 @ stride 16 (64B rows), out accB stride 20; 4 lanes x 64 rows
    run_layer<14, 20, 16, 20, 4, 4, 64>(43, accA, W2, accB, t0, t1, t2, rp_dst, packed, stream);
    silu_bias_kernel<20, 20><<<(N_NODES * 20 + BS - 1) / BS, BS, 0, stream>>>(accB, b2);
    // L3: CIN=20 @ stride 20 (PACKED 8MB), out accC stride 28; 5 lanes x 51 rows
    run_layer<20, 27, 20, 28, 4, 5, 51>(45, accB, W3, accC, t0, t1, t2, rp_dst, packed, stream);
    // final fuses silu(acc+b3) + W4 dot + sigmoid — no silu_bias<27,28> pass.
    final_kernel<<<gN, BS, 0, stream>>>(accC, b3, W4, out);
}